// Round 3
// baseline (1994.228 us; speedup 1.0000x reference)
//
#include <hip/hip_runtime.h>
#include <hip/hip_bf16.h>
#include <cmath>
#include <complex>
#include <vector>
#include <cstring>
#include <cstdint>

// ---------------------------------------------------------------------------
// ShieldingT2Model: correctness-first f32 implementation.
// B=16384, NS=64, NK=32, NL=16, HM=256, HC=128, out = (B,5) f32.
// ws layout (~1.46 MB):
//   mixed   @ 0       : B*5  f32   (327680 B)
//   w202T   @ 327680  : 128*128 f32 (65536 B)
//   wsym000 @ 393216  : 2080*128 f32 (1064960 B)
// C222 sign: reference fixes sign via sign(c[argmax|c|]); the max-|c| family
// has 7 exactly-tied entries of mixed sign, so numpy's pick is resolved by
// SVD fp noise. Majority-positive (+1) failed with absmax 8.94 ~= 2x corr
// tails => reference uses the opposite sign. C222_FLIP = -1.
// ---------------------------------------------------------------------------

#define C222_FLIP -1.0f

#define MIX_WS_OFF  0
#define W202T_OFF   327680
#define WSYM_OFF    393216

struct Coefs {
  float c222[125];   // full (2,2,2) real wigner-3j, [i][j][k]
  float d022[5];     // diag of C022[0,:,:]
  float d202[5];     // diag of C202[:,0,:]
  float d220[5];     // diag of C220[:,:,0]
  float a0, a2, b2;
};

#define FMA8(acc, wa, wb, sv) do { \
  acc[0] = fmaf((wa).x, (sv), acc[0]); \
  acc[1] = fmaf((wa).y, (sv), acc[1]); \
  acc[2] = fmaf((wa).z, (sv), acc[2]); \
  acc[3] = fmaf((wa).w, (sv), acc[3]); \
  acc[4] = fmaf((wb).x, (sv), acc[4]); \
  acc[5] = fmaf((wb).y, (sv), acc[5]); \
  acc[6] = fmaf((wb).z, (sv), acc[6]); \
  acc[7] = fmaf((wb).w, (sv), acc[7]); \
} while (0)

__device__ __forceinline__ float act_silu(float x) {
  // SILU_NORM * silu(x)
  return 1.679f * x / (1.0f + expf(-x));
}

__device__ __forceinline__ float waveReduce64(float v) {
  v += __shfl_xor(v, 32);
  v += __shfl_xor(v, 16);
  v += __shfl_xor(v, 8);
  v += __shfl_xor(v, 4);
  v += __shfl_xor(v, 2);
  v += __shfl_xor(v, 1);
  return v;
}

// ---------------------------------------------------------------------------
// K1: MLP -> weights -> mixed.  32 b per wg, 256 threads.
// ---------------------------------------------------------------------------
__global__ __launch_bounds__(256) void k_prep(
    const float* __restrict__ s, const float* __restrict__ t2s,
    const float* __restrict__ w1, const float* __restrict__ w2,
    const float* __restrict__ w3, const float* __restrict__ gthr,
    float* __restrict__ mixed_ws)
{
  __shared__ float sT[64][36];    // [k][b], padded
  __shared__ float hT[256][36];   // [c][b], holds h1 then h2

  const int tid = threadIdx.x;
  const int b0  = blockIdx.x * 32;

  #pragma unroll
  for (int i = 0; i < 8; i++) {
    int flat = tid + i * 256;
    int bl = flat >> 6, k = flat & 63;
    sT[k][bl] = s[(size_t)(b0 + bl) * 64 + k];
  }
  __syncthreads();

  const int cg = tid & 31, bg = tid >> 5;
  const int c0 = cg * 8, bb0 = bg * 4;

  // ---- h1 = 1.679*silu(s@W1/8), tile 4b x 8c ----
  float acc[4][8];
  #pragma unroll
  for (int j = 0; j < 4; j++)
    #pragma unroll
    for (int i = 0; i < 8; i++) acc[j][i] = 0.f;

  for (int k = 0; k < 64; k++) {
    float4 bv = *(const float4*)&sT[k][bb0];
    float4 wa = *(const float4*)&w1[k * 256 + c0];
    float4 wb = *(const float4*)&w1[k * 256 + c0 + 4];
    const float bvv[4] = {bv.x, bv.y, bv.z, bv.w};
    #pragma unroll
    for (int j = 0; j < 4; j++) { FMA8(acc[j], wa, wb, bvv[j]); }
  }
  #pragma unroll
  for (int j = 0; j < 4; j++)
    #pragma unroll
    for (int i = 0; i < 8; i++)
      hT[c0 + i][bb0 + j] = act_silu(acc[j][i] * 0.125f);
  __syncthreads();

  // ---- h2 = 1.679*silu(h1@W2/16) ----
  float acc2[4][8];
  #pragma unroll
  for (int j = 0; j < 4; j++)
    #pragma unroll
    for (int i = 0; i < 8; i++) acc2[j][i] = 0.f;

  for (int k = 0; k < 256; k++) {
    float4 bv = *(const float4*)&hT[k][bb0];
    float4 wa = *(const float4*)&w2[k * 256 + c0];
    float4 wb = *(const float4*)&w2[k * 256 + c0 + 4];
    const float bvv[4] = {bv.x, bv.y, bv.z, bv.w};
    #pragma unroll
    for (int j = 0; j < 4; j++) { FMA8(acc2[j], wa, wb, bvv[j]); }
  }
  __syncthreads();   // all h1 reads done before overwrite
  #pragma unroll
  for (int j = 0; j < 4; j++)
    #pragma unroll
    for (int i = 0; i < 8; i++)
      hT[c0 + i][bb0 + j] = act_silu(acc2[j][i] * 0.0625f);
  __syncthreads();

  // ---- rel = h2@W3/16 ; gate ; weights ; mixed ----
  const int jj  = tid & 31;   // kernel index
  const int blg = tid >> 5;   // 8 b-groups of 4
  float acc3[4] = {0.f, 0.f, 0.f, 0.f};
  for (int k = 0; k < 256; k++) {
    float wv  = w3[k * 32 + jj];
    float4 hv = *(const float4*)&hT[k][blg * 4];
    acc3[0] = fmaf(hv.x, wv, acc3[0]);
    acc3[1] = fmaf(hv.y, wv, acc3[1]);
    acc3[2] = fmaf(hv.z, wv, acc3[2]);
    acc3[3] = fmaf(hv.w, wv, acc3[3]);
  }
  const float thrv = gthr[jj];
  #pragma unroll
  for (int r = 0; r < 4; r++) {
    int bl = blg * 4 + r;
    int b  = b0 + bl;
    float rel = acc3[r] * 0.0625f;
    const float* tp = t2s + (size_t)(b * 32 + jj) * 5;
    float tv0 = tp[0], tv1 = tp[1], tv2 = tp[2], tv3 = tp[3], tv4 = tp[4];
    float mag  = sqrtf(tv0*tv0 + tv1*tv1 + tv2*tv2 + tv3*tv3 + tv4*tv4);
    float gate = mag / (mag + thrv);
    float w = rel * gate * 0.17677669529663687f;  // 1/sqrt(32)
    float pm0 = w*tv0, pm1 = w*tv1, pm2 = w*tv2, pm3 = w*tv3, pm4 = w*tv4;
    #pragma unroll
    for (int off = 16; off >= 1; off >>= 1) {
      pm0 += __shfl_xor(pm0, off);
      pm1 += __shfl_xor(pm1, off);
      pm2 += __shfl_xor(pm2, off);
      pm3 += __shfl_xor(pm3, off);
      pm4 += __shfl_xor(pm4, off);
    }
    if (jj == 0) {
      float* mp = mixed_ws + (size_t)b * 5;
      mp[0] = pm0; mp[1] = pm1; mp[2] = pm2; mp[3] = pm3; mp[4] = pm4;
    }
  }
}

// ---------------------------------------------------------------------------
// K2: transpose tp2_w202 (128x128) so hv GEMV is lane-coalesced.
// ---------------------------------------------------------------------------
__global__ __launch_bounds__(256) void k_transpose(
    const float* __restrict__ in, float* __restrict__ out)
{
  int idx = blockIdx.x * 256 + threadIdx.x;  // 16384
  int u = idx >> 7, v = idx & 127;
  out[v * 128 + u] = in[u * 128 + v];
}

// ---------------------------------------------------------------------------
// K3: symmetrize tp1_w000 into packed upper-triangular (2080 pairs x 128).
// pair p = base(u) + (v-u), base(u) = u*64 - u(u-1)/2; val = W[u,v]+[v,u] (v>u)
// ---------------------------------------------------------------------------
__global__ __launch_bounds__(256) void k_symW000(
    const float* __restrict__ w, float* __restrict__ wsym)
{
  int u = blockIdx.x;  // 64 blocks
  int base = u * 64 - (u * (u - 1)) / 2;
  int n = (64 - u) * 128;
  for (int idx = threadIdx.x; idx < n; idx += 256) {
    int t = idx >> 7, wc = idx & 127;
    int v = u + t;
    float val = w[(size_t)(u * 64 + v) * 128 + wc];
    if (v > u) val += w[(size_t)(v * 64 + u) * 128 + wc];
    wsym[(size_t)(base + t) * 128 + wc] = val;
  }
}

// ---------------------------------------------------------------------------
// K4: heavy kernel. 32 b per wg, 512 threads.
// Phases: y000(sym) + y220 -> y0L ; tp022+tp202+tp222 -> y2L ; tp2 ; out.
// ---------------------------------------------------------------------------
__global__ __launch_bounds__(512) void k_main(
    const float* __restrict__ s, const float* __restrict__ t2s,
    const float* __restrict__ mixed_ws,
    const float* __restrict__ wsym,  const float* __restrict__ w220,
    const float* __restrict__ w022,  const float* __restrict__ w202,
    const float* __restrict__ w222,
    const float* __restrict__ w2022, const float* __restrict__ w202T,
    const float* __restrict__ w2222,
    const float* __restrict__ csc, float* __restrict__ out, Coefs cf)
{
  __shared__ float sL[32][68];        //  8.7 KB
  __shared__ float tL[32][16][8];     // 16.4 KB ([b][u][i], i in 0..4)
  __shared__ float y0L[32][128];      // 16.4 KB
  __shared__ float y2L[32][5][128];   // 81.9 KB ([b][k][w])
  __shared__ float grL[32][16];       //  2.0 KB
  __shared__ float GL[32][25];        //  3.2 KB
  __shared__ float QL[32][16][5];     // 10.2 KB
  __shared__ float cL222[125];
  __shared__ float corrAcc[32][5];
  __shared__ float pPL[32][25];
  // total ~143 KB < 160 KB

  const int tid = threadIdx.x;
  const int b0  = blockIdx.x * 32;

  float dk022[5], dk202[5], dk220[5];
  #pragma unroll
  for (int k = 0; k < 5; k++) {
    dk022[k] = cf.d022[k]; dk202[k] = cf.d202[k]; dk220[k] = cf.d220[k];
  }

  // ---- phase 0: stage s, t, constants; zero accumulators ----
  if (tid == 0) {
    #pragma unroll
    for (int i = 0; i < 125; i++) cL222[i] = cf.c222[i];  // static idx -> kernarg loads
  }
  for (int idx = tid; idx < 2048; idx += 512) {
    int bl = idx >> 6, k = idx & 63;
    sL[bl][k] = s[(size_t)(b0 + bl) * 64 + k];
  }
  // t tensor: first 15 kernels + sum of all 32 (built directly from t2s)
  for (int idx = tid; idx < 2560; idx += 512) {
    int bl = idx / 80, rem = idx - bl * 80;
    int u = rem / 5, m = rem - u * 5;
    int b = b0 + bl;
    float v;
    if (u < 15) v = t2s[(size_t)(b * 32 + u) * 5 + m];
    else {
      v = 0.f;
      for (int kk = 0; kk < 32; kk++) v += t2s[(size_t)(b * 32 + kk) * 5 + m];
    }
    tL[bl][u][m] = v;
  }
  for (int idx = tid; idx < 160; idx += 512) corrAcc[idx / 5][idx % 5] = 0.f;
  for (int idx = tid; idx < 800; idx += 512) pPL[idx / 25][idx % 25] = 0.f;
  __syncthreads();

  const int xw = tid & 15;   // w-group: w = xw*8 + [0..7]
  const int bl = tid >> 4;   // 0..31
  const int w0 = xw * 8;

  // ================= phase 1: y000 (symmetrized) + y220 =================
  float y0acc[8] = {0.f,0.f,0.f,0.f,0.f,0.f,0.f,0.f};
  {
    int base = 0;
    for (int u = 0; u < 64; u++) {
      const int len = 64 - u;
      float su = sL[bl][u];
      float z[8] = {0.f,0.f,0.f,0.f,0.f,0.f,0.f,0.f};
      const float* Wu = wsym + (size_t)base * 128 + w0;
      for (int t = 0; t < len; t++) {
        float sv = sL[bl][u + t];
        const float* p = Wu + (size_t)t * 128;
        float4 wa = *(const float4*)p;
        float4 wb = *(const float4*)(p + 4);
        FMA8(z, wa, wb, sv);
      }
      #pragma unroll
      for (int wi = 0; wi < 8; wi++) y0acc[wi] = fmaf(su, z[wi], y0acc[wi]);
      base += len;
    }
  }
  // y220: gram rows with C220 diag
  for (int u = 0; u < 16; u++) {
    {
      int bb = tid >> 4, vv = tid & 15;  // 512 = 32*16 exactly
      float g = 0.f;
      #pragma unroll
      for (int m = 0; m < 5; m++)
        g = fmaf(dk220[m] * tL[bb][u][m], tL[bb][vv][m], g);
      grL[bb][vv] = g;
    }
    __syncthreads();
    const float* Wu = w220 + (size_t)(u * 16) * 128 + w0;
    for (int v = 0; v < 16; v++) {
      float gv = grL[bl][v];
      const float* p = Wu + (size_t)v * 128;
      float4 wa = *(const float4*)p;
      float4 wb = *(const float4*)(p + 4);
      FMA8(y0acc, wa, wb, gv);
    }
    __syncthreads();
  }
  #pragma unroll
  for (int wi = 0; wi < 8; wi++) y0L[bl][w0 + wi] = cf.a0 * y0acc[wi];

  // ================= phases 2-4: y2 =================
  float y2acc[5][8];
  #pragma unroll
  for (int k = 0; k < 5; k++)
    #pragma unroll
    for (int wi = 0; wi < 8; wi++) y2acc[k][wi] = 0.f;

  // ---- tp022: sum_v (sum_u W022[u,v,w] s_u) * d022[k] * t[v,k] ----
  for (int v = 0; v < 16; v++) {
    float accA[8] = {0.f,0.f,0.f,0.f,0.f,0.f,0.f,0.f};
    for (int u4 = 0; u4 < 16; u4++) {
      float4 s4 = *(const float4*)&sL[bl][u4 * 4];
      const float sv[4] = {s4.x, s4.y, s4.z, s4.w};
      #pragma unroll
      for (int ui = 0; ui < 4; ui++) {
        const float* p = w022 + (size_t)((u4 * 4 + ui) * 16 + v) * 128 + w0;
        float4 wa = *(const float4*)p;
        float4 wb = *(const float4*)(p + 4);
        FMA8(accA, wa, wb, sv[ui]);
      }
    }
    #pragma unroll
    for (int k = 0; k < 5; k++) {
      float fk = dk022[k] * tL[bl][v][k];
      #pragma unroll
      for (int wi = 0; wi < 8; wi++) y2acc[k][wi] = fmaf(fk, accA[wi], y2acc[k][wi]);
    }
  }
  // ---- tp202: sum_u (sum_v W202[u,v,w] s_v) * d202[k] * t[u,k] ----
  for (int u = 0; u < 16; u++) {
    float accB[8] = {0.f,0.f,0.f,0.f,0.f,0.f,0.f,0.f};
    for (int v4 = 0; v4 < 16; v4++) {
      float4 s4 = *(const float4*)&sL[bl][v4 * 4];
      const float sv[4] = {s4.x, s4.y, s4.z, s4.w};
      #pragma unroll
      for (int vi = 0; vi < 4; vi++) {
        const float* p = w202 + (size_t)(u * 64 + v4 * 4 + vi) * 128 + w0;
        float4 wa = *(const float4*)p;
        float4 wb = *(const float4*)(p + 4);
        FMA8(accB, wa, wb, sv[vi]);
      }
    }
    #pragma unroll
    for (int k = 0; k < 5; k++) {
      float fk = dk202[k] * tL[bl][u][k];
      #pragma unroll
      for (int wi = 0; wi < 8; wi++) y2acc[k][wi] = fmaf(fk, accB[wi], y2acc[k][wi]);
    }
  }
  // ---- tp222: per u, coop G/Q then accumulate ----
  for (int u = 0; u < 16; u++) {
    for (int idx = tid; idx < 800; idx += 512) {
      int bb = idx / 25, jk = idx - bb * 25;
      float g = 0.f;
      #pragma unroll
      for (int ii = 0; ii < 5; ii++)
        g = fmaf(cL222[ii * 25 + jk], tL[bb][u][ii], g);
      GL[bb][jk] = g;
    }
    __syncthreads();
    for (int idx = tid; idx < 2560; idx += 512) {
      int bb = idx / 80, rem = idx - bb * 80;
      int vv = rem / 5, kk = rem - vv * 5;
      float q = 0.f;
      #pragma unroll
      for (int jj = 0; jj < 5; jj++)
        q = fmaf(GL[bb][jj * 5 + kk], tL[bb][vv][jj], q);
      QL[bb][vv][kk] = q;
    }
    __syncthreads();
    for (int v = 0; v < 16; v++) {
      const float* p = w222 + (size_t)(u * 16 + v) * 128 + w0;
      float4 wa = *(const float4*)p;
      float4 wb = *(const float4*)(p + 4);
      #pragma unroll
      for (int k = 0; k < 5; k++) {
        float qv = QL[bl][v][k];
        FMA8(y2acc[k], wa, wb, qv);
      }
    }
    __syncthreads();
  }
  // scale + store y2
  #pragma unroll
  for (int k = 0; k < 5; k++)
    #pragma unroll
    for (int wi = 0; wi < 8; wi++)
      y2L[bl][k][w0 + wi] = cf.a2 * y2acc[k][wi];
  __syncthreads();

  // ================= phase 5: tp2 =================
  const int xv = tid & 127;   // v (or u) index
  const int g4 = tid >> 7;    // 0..3 -> 8 b's each

  // ---- gv[v] = sum_u W2022[u,v] y0[u]; fold d022[k]*sum_v gv*y2[:,k,v] ----
  {
    float gAcc[8] = {0.f,0.f,0.f,0.f,0.f,0.f,0.f,0.f};
    for (int u4 = 0; u4 < 32; u4++) {
      float wv[4];
      #pragma unroll
      for (int uu = 0; uu < 4; uu++) wv[uu] = w2022[(size_t)(u4 * 4 + uu) * 128 + xv];
      #pragma unroll
      for (int r = 0; r < 8; r++) {
        float4 yv = *(const float4*)&y0L[g4 * 8 + r][u4 * 4];
        gAcc[r] = fmaf(wv[0], yv.x, gAcc[r]);
        gAcc[r] = fmaf(wv[1], yv.y, gAcc[r]);
        gAcc[r] = fmaf(wv[2], yv.z, gAcc[r]);
        gAcc[r] = fmaf(wv[3], yv.w, gAcc[r]);
      }
    }
    #pragma unroll
    for (int r = 0; r < 8; r++) {
      int b = g4 * 8 + r;
      #pragma unroll
      for (int k = 0; k < 5; k++) {
        float v = waveReduce64(gAcc[r] * y2L[b][k][xv]);
        if ((tid & 63) == 0) atomicAdd(&corrAcc[b][k], dk022[k] * v);
      }
    }
  }
  // ---- hv[u] = sum_v W2202[u,v] y0[v] (via W202T); fold d202[k]*sum_u hv*y2[:,k,u]
  {
    float hAcc[8] = {0.f,0.f,0.f,0.f,0.f,0.f,0.f,0.f};
    for (int v4 = 0; v4 < 32; v4++) {
      float wv[4];
      #pragma unroll
      for (int vv = 0; vv < 4; vv++) wv[vv] = w202T[(size_t)(v4 * 4 + vv) * 128 + xv];
      #pragma unroll
      for (int r = 0; r < 8; r++) {
        float4 yv = *(const float4*)&y0L[g4 * 8 + r][v4 * 4];
        hAcc[r] = fmaf(wv[0], yv.x, hAcc[r]);
        hAcc[r] = fmaf(wv[1], yv.y, hAcc[r]);
        hAcc[r] = fmaf(wv[2], yv.z, hAcc[r]);
        hAcc[r] = fmaf(wv[3], yv.w, hAcc[r]);
      }
    }
    #pragma unroll
    for (int r = 0; r < 8; r++) {
      int b = g4 * 8 + r;
      #pragma unroll
      for (int k = 0; k < 5; k++) {
        float v = waveReduce64(hAcc[r] * y2L[b][k][xv]);
        if ((tid & 63) == 0) atomicAdd(&corrAcc[b][k], dk202[k] * v);
      }
    }
  }
  // ---- Zi[v,i] = sum_u W2222[u,v] y2[u,i]; P[i,j] = sum_v Zi[v,i] y2[v,j] ----
  for (int i = 0; i < 5; i++) {
    float zAcc[8] = {0.f,0.f,0.f,0.f,0.f,0.f,0.f,0.f};
    for (int u4 = 0; u4 < 32; u4++) {
      float wv[4];
      #pragma unroll
      for (int uu = 0; uu < 4; uu++) wv[uu] = w2222[(size_t)(u4 * 4 + uu) * 128 + xv];
      #pragma unroll
      for (int r = 0; r < 8; r++) {
        float4 yv = *(const float4*)&y2L[g4 * 8 + r][i][u4 * 4];
        zAcc[r] = fmaf(wv[0], yv.x, zAcc[r]);
        zAcc[r] = fmaf(wv[1], yv.y, zAcc[r]);
        zAcc[r] = fmaf(wv[2], yv.z, zAcc[r]);
        zAcc[r] = fmaf(wv[3], yv.w, zAcc[r]);
      }
    }
    #pragma unroll
    for (int r = 0; r < 8; r++) {
      int b = g4 * 8 + r;
      #pragma unroll
      for (int jj = 0; jj < 5; jj++) {
        float v = waveReduce64(zAcc[r] * y2L[b][jj][xv]);
        if ((tid & 63) == 0) atomicAdd(&pPL[b][i * 5 + jj], v);
      }
    }
  }
  __syncthreads();

  // ---- epilogue: corr222 from P, combine, add mixed ----
  if (tid < 160) {
    int bb = tid / 5, k = tid - bb * 5;
    float c2 = 0.f;
    #pragma unroll
    for (int ii = 0; ii < 5; ii++)
      #pragma unroll
      for (int jj = 0; jj < 5; jj++)
        c2 = fmaf(cL222[ii * 25 + jj * 5 + k], pPL[bb][ii * 5 + jj], c2);
    float tot = corrAcc[bb][k] + c2;
    int b = b0 + bb;
    out[(size_t)b * 5 + k] = mixed_ws[(size_t)b * 5 + k] + csc[0] * cf.b2 * tot;
  }
}

// ---------------------------------------------------------------------------
// Host: replicate reference's wigner-3j computation (RREF null space).
// ---------------------------------------------------------------------------
namespace {

using cplx = std::complex<double>;

static void su2_gen(int l, std::vector<cplx>& Jx, std::vector<cplx>& Jy,
                    std::vector<cplx>& Jz) {
  int d = 2 * l + 1;
  Jx.assign((size_t)d * d, cplx(0, 0));
  Jy.assign((size_t)d * d, cplx(0, 0));
  Jz.assign((size_t)d * d, cplx(0, 0));
  for (int a = 0; a < d; a++) Jz[(size_t)a * d + a] = cplx(a - l, 0);
  for (int r = 1; r < d; r++) {
    double m = (r - 1) - l;
    double v = std::sqrt(l * (l + 1.0) - m * (m + 1.0));
    Jx[(size_t)r * d + (r - 1)] += cplx(v / 2, 0);
    Jx[(size_t)(r - 1) * d + r] += cplx(v / 2, 0);
    Jy[(size_t)r * d + (r - 1)] += cplx(0, -v / 2);
    Jy[(size_t)(r - 1) * d + r] += cplx(0, v / 2);
  }
}

static void real_basis(int l, std::vector<cplx>& U) {
  int d = 2 * l + 1;
  U.assign((size_t)d * d, cplx(0, 0));
  U[(size_t)l * d + l] = cplx(1, 0);
  double is2 = 1.0 / std::sqrt(2.0);
  for (int m = 1; m <= l; m++) {
    double sgn = (m % 2 == 0) ? 1.0 : -1.0;
    U[(size_t)(l + m) * d + (l + m)] = cplx(sgn * is2, 0);
    U[(size_t)(l + m) * d + (l - m)] = cplx(is2, 0);
    U[(size_t)(l - m) * d + (l - m)] = cplx(0, is2);
    U[(size_t)(l - m) * d + (l + m)] = cplx(0, -sgn * is2);
  }
}

static void real_gens(int l, std::vector<double> G[3]) {
  int d = 2 * l + 1;
  if (l == 0) { for (int a = 0; a < 3; a++) G[a].assign(1, 0.0); return; }
  std::vector<cplx> J[3];
  su2_gen(l, J[0], J[1], J[2]);
  std::vector<cplx> U;
  real_basis(l, U);
  for (int a = 0; a < 3; a++) {
    std::vector<cplx> T((size_t)d * d, cplx(0, 0));
    for (int i = 0; i < d; i++)
      for (int k = 0; k < d; k++) {
        cplx s(0, 0);
        for (int j = 0; j < d; j++)
          s += U[(size_t)i * d + j] * (cplx(0, -1) * J[a][(size_t)j * d + k]);
        T[(size_t)i * d + k] = s;
      }
    G[a].assign((size_t)d * d, 0.0);
    for (int i = 0; i < d; i++)
      for (int k = 0; k < d; k++) {
        cplx s(0, 0);
        for (int j = 0; j < d; j++)
          s += T[(size_t)i * d + j] * std::conj(U[(size_t)k * d + j]);
        G[a][(size_t)i * d + k] = s.real();
      }
  }
}

static void w3j_host(int l1, int l2, int l3, float* out) {
  int d1 = 2 * l1 + 1, d2 = 2 * l2 + 1, d3 = 2 * l3 + 1;
  int D = d1 * d2 * d3;
  std::vector<double> G1[3], G2[3], G3[3];
  real_gens(l1, G1); real_gens(l2, G2); real_gens(l3, G3);
  int R = 3 * D;
  std::vector<double> M((size_t)R * D, 0.0);
  for (int a = 0; a < 3; a++) {
    double* Ma = &M[(size_t)a * D * D];
    for (int i1 = 0; i1 < d1; i1++)
      for (int j1 = 0; j1 < d1; j1++) {
        double g = G1[a][(size_t)i1 * d1 + j1];
        if (g == 0.0) continue;
        for (int i2 = 0; i2 < d2; i2++)
          for (int i3 = 0; i3 < d3; i3++)
            Ma[(size_t)((i1 * d2 + i2) * d3 + i3) * D + ((j1 * d2 + i2) * d3 + i3)] += g;
      }
    for (int i2 = 0; i2 < d2; i2++)
      for (int j2 = 0; j2 < d2; j2++) {
        double g = G2[a][(size_t)i2 * d2 + j2];
        if (g == 0.0) continue;
        for (int i1 = 0; i1 < d1; i1++)
          for (int i3 = 0; i3 < d3; i3++)
            Ma[(size_t)((i1 * d2 + i2) * d3 + i3) * D + ((i1 * d2 + j2) * d3 + i3)] += g;
      }
    for (int i3 = 0; i3 < d3; i3++)
      for (int j3 = 0; j3 < d3; j3++) {
        double g = G3[a][(size_t)i3 * d3 + j3];
        if (g == 0.0) continue;
        for (int i1 = 0; i1 < d1; i1++)
          for (int i2 = 0; i2 < d2; i2++)
            Ma[(size_t)((i1 * d2 + i2) * d3 + i3) * D + ((i1 * d2 + i2) * d3 + j3)] += g;
      }
  }
  // RREF null space (null dim == 1)
  std::vector<int> pivcol;
  int rank = 0;
  for (int col = 0; col < D && rank < R; col++) {
    int pr = -1; double pv = 1e-9;
    for (int r = rank; r < R; r++) {
      double av = std::fabs(M[(size_t)r * D + col]);
      if (av > pv) { pv = av; pr = r; }
    }
    if (pr < 0) continue;
    if (pr != rank)
      for (int c = 0; c < D; c++) std::swap(M[(size_t)pr * D + c], M[(size_t)rank * D + c]);
    double inv = 1.0 / M[(size_t)rank * D + col];
    for (int c = 0; c < D; c++) M[(size_t)rank * D + c] *= inv;
    for (int r = 0; r < R; r++) {
      if (r == rank) continue;
      double f = M[(size_t)r * D + col];
      if (f != 0.0)
        for (int c = 0; c < D; c++) M[(size_t)r * D + c] -= f * M[(size_t)rank * D + c];
    }
    pivcol.push_back(col);
    rank++;
  }
  std::vector<char> isp(D, 0);
  for (int c : pivcol) isp[c] = 1;
  int fc = 0;
  for (int c = 0; c < D; c++) if (!isp[c]) { fc = c; break; }
  std::vector<double> x(D, 0.0);
  x[fc] = 1.0;
  for (int r = 0; r < rank; r++) x[pivcol[r]] = -M[(size_t)r * D + fc];
  double n = 0;
  for (double v : x) n += v * v;
  n = std::sqrt(n);
  for (int c = 0; c < D; c++) x[c] /= n;
  // Sign canonicalization: among entries tied (within 0.1%) for max |x|,
  // make the MAJORITY sign positive. For tensors whose tied family is
  // all-same-sign (C000 and the diagonal C022/C202/C220) this matches the
  // reference's sign(c[argmax|c|]) exactly. For C222 the family is mixed-sign
  // and the reference's fp-noise argmax picked the OTHER branch (see
  // C222_FLIP applied by the caller).
  double best = 0;
  for (int c = 0; c < D; c++) { double av = std::fabs(x[c]); if (av > best) best = av; }
  double ssum = 0;
  for (int c = 0; c < D; c++) {
    double av = std::fabs(x[c]);
    if (av >= best * 0.999) ssum += (x[c] >= 0 ? 1.0 : -1.0);
  }
  double sgn = (ssum >= 0) ? 1.0 : -1.0;
  for (int c = 0; c < D; c++) out[c] = (float)(x[c] * sgn);
}

}  // namespace

// ---------------------------------------------------------------------------
extern "C" void kernel_launch(void* const* d_in, const int* in_sizes, int n_in,
                              void* d_out, int out_size, void* d_ws, size_t ws_size,
                              hipStream_t stream)
{
  (void)in_sizes; (void)n_in; (void)out_size; (void)ws_size;

  const float* s     = (const float*)d_in[0];
  const float* t2s   = (const float*)d_in[1];
  const float* w1    = (const float*)d_in[2];
  const float* w2    = (const float*)d_in[3];
  const float* w3    = (const float*)d_in[4];
  const float* gthr  = (const float*)d_in[5];
  const float* w000  = (const float*)d_in[6];
  const float* w220  = (const float*)d_in[7];
  const float* w022  = (const float*)d_in[8];
  const float* w202  = (const float*)d_in[9];
  const float* w222  = (const float*)d_in[10];
  const float* w2022 = (const float*)d_in[11];
  const float* w2202 = (const float*)d_in[12];
  const float* w2222 = (const float*)d_in[13];
  const float* csc   = (const float*)d_in[14];
  float* out = (float*)d_out;

  char* ws = (char*)d_ws;
  float* mixed_ws = (float*)(ws + MIX_WS_OFF);
  float* w202T    = (float*)(ws + W202T_OFF);
  float* wsym     = (float*)(ws + WSYM_OFF);

  // Host-side wigner-3j constants (runs every call; ~ms, off the GPU stream)
  Coefs cf;
  {
    float c000v[1], c022v[25], c202v[25], c220v[25];
    w3j_host(0, 0, 0, c000v);
    w3j_host(0, 2, 2, c022v);
    w3j_host(2, 0, 2, c202v);
    w3j_host(2, 2, 0, c220v);
    w3j_host(2, 2, 2, cf.c222);
    for (int i = 0; i < 125; i++) cf.c222[i] *= C222_FLIP;
    for (int k = 0; k < 5; k++) {
      cf.d022[k] = c022v[k * 5 + k];   // C022[0,k,k]
      cf.d202[k] = c202v[k * 5 + k];   // C202[k,0,k]
      cf.d220[k] = c220v[k * 5 + k];   // C220[k,k,0]
    }
    (void)c000v;  // == 1.0 exactly
    cf.a0 = (float)std::sqrt(1.0 / (64.0 * 64.0 + 16.0 * 16.0));
    cf.a2 = (float)std::sqrt(5.0 / (2.0 * 64.0 * 16.0 + 16.0 * 16.0));
    cf.b2 = (float)std::sqrt(5.0 / (3.0 * 128.0 * 128.0));
  }

  hipLaunchKernelGGL(k_prep, dim3(512), dim3(256), 0, stream,
                     s, t2s, w1, w2, w3, gthr, mixed_ws);
  hipLaunchKernelGGL(k_transpose, dim3(64), dim3(256), 0, stream, w2202, w202T);
  hipLaunchKernelGGL(k_symW000, dim3(64), dim3(256), 0, stream, w000, wsym);
  hipLaunchKernelGGL(k_main, dim3(512), dim3(512), 0, stream,
                     s, t2s, mixed_ws, wsym, w220, w022, w202, w222,
                     w2022, w202T, w2222, csc, out, cf);
}